// Round 8
// baseline (303.509 us; speedup 1.0000x reference)
//
#include <hip/hip_runtime.h>
#include <hip/hip_bf16.h>

#define BB 2
#define NN 256
#define IN_DIM 256
#define EDGE_DIM 16
#define HH 8
#define DD 64
#define INNER 512
#define BH (BB*HH)
#define II 4   // i-rows per attn block

// Fused q/k/v projection, LDS-staged, float4 staging.
// Block: 256 threads = one 256-col half; 4 rows; k in chunks of 4.
// z==0: q row-major  z==1: k transposed  z==2: v row-major
__global__ __launch_bounds__(256, 4)
void proj_kernel(const float* __restrict__ nodes,
                 const float* __restrict__ Wq, const float* __restrict__ bq,
                 const float* __restrict__ Wk, const float* __restrict__ bk,
                 const float* __restrict__ Wv, const float* __restrict__ bv,
                 float* __restrict__ qf, float* __restrict__ kT,
                 float* __restrict__ vf) {
    const int z = blockIdx.z;
    const float* W; const float* bias; float* out; int mode;
    if (z == 0)      { W = Wq; bias = bq; out = qf; mode = 0; }
    else if (z == 1) { W = Wk; bias = bk; out = kT; mode = 1; }
    else             { W = Wv; bias = bv; out = vf; mode = 0; }

    const int tid = threadIdx.x;
    const int half = blockIdx.x;     // 0..1
    const int r0 = blockIdx.y * 4;   // 4 rows per block

    __shared__ float4 nsh4[4][IN_DIM / 4];   // 4 KB
    {   // stage 4 rows (256 float4), 1 per thread, coalesced
        int rr = tid >> 6, c4 = tid & 63;
        nsh4[rr][c4] = ((const float4*)nodes)[(r0 + rr) * (IN_DIM / 4) + c4];
    }
    __syncthreads();

    const int col = half * 256 + tid;
    float acc[4] = {0.f, 0.f, 0.f, 0.f};
#pragma unroll 4
    for (int kc = 0; kc < IN_DIM / 4; ++kc) {
        float4 n0 = nsh4[0][kc], n1 = nsh4[1][kc], n2 = nsh4[2][kc], n3 = nsh4[3][kc];
        float w0 = W[(kc * 4 + 0) * INNER + col];
        float w1 = W[(kc * 4 + 1) * INNER + col];
        float w2 = W[(kc * 4 + 2) * INNER + col];
        float w3 = W[(kc * 4 + 3) * INNER + col];
        acc[0] += n0.x * w0 + n0.y * w1 + n0.z * w2 + n0.w * w3;
        acc[1] += n1.x * w0 + n1.y * w1 + n1.z * w2 + n1.w * w3;
        acc[2] += n2.x * w0 + n2.y * w1 + n2.z * w2 + n2.w * w3;
        acc[3] += n3.x * w0 + n3.y * w1 + n3.z * w2 + n3.w * w3;
    }
    const float bv2 = bias[col];
    const int h = col >> 6, d = col & 63;
#pragma unroll
    for (int rr = 0; rr < 4; ++rr) {
        int r = r0 + rr;
        int b = r >> 8, n = r & 255;
        float val = acc[rr] + bv2;
        if (mode == 0)
            out[((b * HH + h) * NN + n) * DD + d] = val;
        else
            out[((b * HH + h) * DD + d) * NN + n] = val;
    }
}

// means[i] = mean_j sim[bh=0, i, j]   (the reference's [0]-sliced mean)
__global__ void means_kernel(const float* __restrict__ q,   // (BH,N,D)
                             const float* __restrict__ kT,  // (BH,D,N)
                             const float* __restrict__ edges,
                             const float* __restrict__ We,
                             const float* __restrict__ be,
                             float* __restrict__ means) {
    const int i = blockIdx.x;
    const int tid = threadIdx.x;
    __shared__ float qsh[DD];
    __shared__ float tsh[EDGE_DIM + 1];
    __shared__ float wred[4];
    if (tid < DD) qsh[tid] = q[i * DD + tid];    // bh = 0
    __syncthreads();
    if (tid < EDGE_DIM) {
        float s = 0.f;
        for (int d = 0; d < DD; ++d) s += qsh[d] * We[tid * INNER + d];  // h=0
        tsh[tid] = s;
    } else if (tid == EDGE_DIM) {
        float s = 0.f;
        for (int d = 0; d < DD; ++d) s += qsh[d] * be[d];
        tsh[EDGE_DIM] = s;
    }
    __syncthreads();
    const int j = tid;
    float sim = 0.f;
    for (int d = 0; d < DD; ++d) sim += qsh[d] * kT[d * NN + j];  // bh = 0
    float ed = 0.f;
    const float* erow = &edges[(i * NN + j) * EDGE_DIM];          // b = 0
#pragma unroll
    for (int c = 0; c < EDGE_DIM; ++c) ed += erow[c] * tsh[c];
    sim = (sim + ed + tsh[EDGE_DIM]) * 0.125f;
    float s = sim;
    for (int o = 32; o > 0; o >>= 1) s += __shfl_down(s, o, 64);
    if ((tid & 63) == 0) wred[tid >> 6] = s;
    __syncthreads();
    if (tid == 0) means[i] = (wred[0] + wred[1] + wred[2] + wred[3]) * (1.f / NN);
}

// One block per (bh, i-tile of II=4 rows), 256 threads, 1024 blocks (4/CU).
// q tile transposed in LDS -> score loop reads one uniform float4 per d.
// Softmax normalization deferred to the epilogue; numerators live in LDS.
__global__ __launch_bounds__(256, 4)
void attn_kernel(const float* __restrict__ q,
                 const float* __restrict__ kT,
                 const float* __restrict__ v,
                 const float* __restrict__ edges,
                 const float* __restrict__ adj,
                 const float* __restrict__ We,
                 const float* __restrict__ be,
                 const float* __restrict__ means,
                 float* __restrict__ out) {
    const int blk = blockIdx.x;           // BH * 64 = 1024
    const int bh = blk >> 6;
    const int it = blk & 63;
    const int i0 = it * II;
    const int b = bh >> 3, h = bh & 7;
    const int tid = threadIdx.x;          // 0..255
    const int j = tid;
    const int w = tid >> 6;               // wave 0..3

    __shared__ float qshT[DD][II];                // 1 KB (transposed)
    __shared__ float tsh[II][EDGE_DIM + 1];       // 272 B
    __shared__ float xsh[II][NN];                 // 4 KB (numerators)
    __shared__ float red[4][II][DD];              // 4 KB
    __shared__ float wred2[16][II][EDGE_DIM];     // 4 KB
    __shared__ float wsh[II][EDGE_DIM];
    __shared__ float dred[II][4];
    __shared__ float msh[II];
    __shared__ float dinv[II];
    __shared__ float scoef_sh[II];

    {   // stage q rows transposed: 256 elements, one per thread
        int ii = tid >> 6, d = tid & 63;
        qshT[d][ii] = q[(bh * NN + i0 + ii) * DD + d];
    }
    if (tid < II) msh[tid] = means[i0 + tid];
    __syncthreads();

    if (tid < II * (EDGE_DIM + 1)) {
        int ii = tid / (EDGE_DIM + 1), c = tid % (EDGE_DIM + 1);
        float s = 0.f;
        if (c < EDGE_DIM) {
            for (int d = 0; d < DD; ++d) s += qshT[d][ii] * We[c * INNER + h * DD + d];
        } else {
            for (int d = 0; d < DD; ++d) s += qshT[d][ii] * be[h * DD + d];
        }
        tsh[ii][c] = s;
    }
    __syncthreads();

    // --- scores: one uniform float4 q read + 4 FMA per d ---
    float sim[II] = {0.f, 0.f, 0.f, 0.f};
    const float* kbase = &kT[bh * DD * NN];
    for (int d = 0; d < DD; ++d) {
        float kv = kbase[d * NN + j];
        float4 q4 = *(const float4*)&qshT[d][0];
        sim[0] += q4.x * kv;
        sim[1] += q4.y * kv;
        sim[2] += q4.z * kv;
        sim[3] += q4.w * kv;
    }

    // --- per row: edge term, exp, mask; numerator -> LDS; denom reduce ---
#pragma unroll
    for (int ii = 0; ii < II; ++ii) {
        const float4* e4 = (const float4*)&edges[((b * NN + i0 + ii) * NN + j) * EDGE_DIM];
        float4 e0 = e4[0], e1 = e4[1], e2 = e4[2], e3 = e4[3];
        float ed = tsh[ii][EDGE_DIM];
        ed += e0.x * tsh[ii][0] + e0.y * tsh[ii][1] + e0.z * tsh[ii][2] + e0.w * tsh[ii][3];
        ed += e1.x * tsh[ii][4] + e1.y * tsh[ii][5] + e1.z * tsh[ii][6] + e1.w * tsh[ii][7];
        ed += e2.x * tsh[ii][8] + e2.y * tsh[ii][9] + e2.z * tsh[ii][10] + e2.w * tsh[ii][11];
        ed += e3.x * tsh[ii][12] + e3.y * tsh[ii][13] + e3.z * tsh[ii][14] + e3.w * tsh[ii][15];
        float s = (sim[ii] + ed) * 0.125f;
        float x = __expf(s - msh[ii]) * adj[(b * NN + i0 + ii) * NN + j];
        xsh[ii][j] = x;
        for (int o = 32; o > 0; o >>= 1) x += __shfl_down(x, o, 64);
        if ((tid & 63) == 0) dred[ii][w] = x;
    }
    __syncthreads();
    if (tid < II) {
        float denom = dred[tid][0] + dred[tid][1] + dred[tid][2] + dred[tid][3];
        scoef_sh[tid] = (denom == 0.f) ? 0.f : 1.f;
        dinv[tid] = (denom == 0.f) ? 1.f : 1.f / denom;
    }
    __syncthreads();

    // --- x @ v (numerators): 4 partials of 64 j, float4 over j ---
    {
        const int d = tid & 63, part = tid >> 6;
        float acc[II] = {0.f, 0.f, 0.f, 0.f};
        const float* vb = &v[(bh * NN + part * 64) * DD + d];
        for (int jj4 = 0; jj4 < 16; ++jj4) {
            float av0 = vb[(jj4 * 4 + 0) * DD];
            float av1 = vb[(jj4 * 4 + 1) * DD];
            float av2 = vb[(jj4 * 4 + 2) * DD];
            float av3 = vb[(jj4 * 4 + 3) * DD];
#pragma unroll
            for (int ii = 0; ii < II; ++ii) {
                float4 x4 = *(const float4*)&xsh[ii][part * 64 + jj4 * 4];
                acc[ii] += x4.x * av0 + x4.y * av1 + x4.z * av2 + x4.w * av3;
            }
        }
#pragma unroll
        for (int ii = 0; ii < II; ++ii) red[part][ii][d] = acc[ii];
    }
    // --- w~[ii][c] = sum_j x[ii][j] * edges[b,i0+ii,j,c]: 16 partials of 16 j ---
    {
        const int c = tid & 15, p = tid >> 4;
        float accw[II] = {0.f, 0.f, 0.f, 0.f};
        for (int jj = 0; jj < 16; ++jj) {
            int jr = p * 16 + jj;
#pragma unroll
            for (int ii = 0; ii < II; ++ii)
                accw[ii] += xsh[ii][jr] *
                            edges[((b * NN + i0 + ii) * NN + jr) * EDGE_DIM + c];
        }
#pragma unroll
        for (int ii = 0; ii < II; ++ii) wred2[p][ii][c] = accw[ii];
    }
    __syncthreads();
    if (tid < II * EDGE_DIM) {
        int ii = tid >> 4, c = tid & 15;
        float t = 0.f;
#pragma unroll
        for (int p = 0; p < 16; ++p) t += wred2[p][ii][c];
        wsh[ii][c] = t;
    }
    __syncthreads();

    // --- epilogue: II*DD = 256 outputs, one per thread; normalize once ---
    {
        int ii = tid >> 6, d = tid & 63;
        float o = red[0][ii][d] + red[1][ii][d] + red[2][ii][d] + red[3][ii][d];
#pragma unroll
        for (int c = 0; c < EDGE_DIM; ++c)
            o += wsh[ii][c] * We[c * INNER + h * DD + d];
        out[(b * NN + i0 + ii) * INNER + h * DD + d] =
            o * dinv[ii] + scoef_sh[ii] * be[h * DD + d];
    }
}

extern "C" void kernel_launch(void* const* d_in, const int* in_sizes, int n_in,
                              void* d_out, int out_size, void* d_ws, size_t ws_size,
                              hipStream_t stream) {
    const float* nodes = (const float*)d_in[0];
    const float* edges = (const float*)d_in[1];
    const float* adj   = (const float*)d_in[2];
    const float* Wq = (const float*)d_in[3];
    const float* bq = (const float*)d_in[4];
    const float* Wk = (const float*)d_in[5];
    const float* bk = (const float*)d_in[6];
    const float* Wv = (const float*)d_in[7];
    const float* bv = (const float*)d_in[8];
    const float* We = (const float*)d_in[9];
    const float* be = (const float*)d_in[10];
    float* out = (float*)d_out;

    float* qf = (float*)d_ws;            // BH*N*D
    float* kT = qf + BH * NN * DD;       // BH*D*N
    float* vf = kT + BH * NN * DD;       // BH*N*D
    float* means = vf + BH * NN * DD;    // N

    hipLaunchKernelGGL(proj_kernel, dim3(2, 128, 3), dim3(256), 0, stream,
                       nodes, Wq, bq, Wk, bk, Wv, bv, qf, kT, vf);
    hipLaunchKernelGGL(means_kernel, dim3(NN), dim3(256), 0, stream,
                       qf, kT, edges, We, be, means);
    hipLaunchKernelGGL(attn_kernel, dim3(BH * (NN / II)), dim3(256), 0, stream,
                       qf, kT, vf, edges, adj, We, be, means, out);
}

// Round 9
// 127.279 us; speedup vs baseline: 2.3846x; 2.3846x over previous
//
#include <hip/hip_runtime.h>
#include <hip/hip_bf16.h>

#define BB 2
#define NN 256
#define IN_DIM 256
#define EDGE_DIM 16
#define HH 8
#define DD 64
#define INNER 512
#define BH (BB*HH)
#define II 8   // i-rows per attn block (r6 proven shape)

// Fused q/k/v projection, LDS-staged (r6-identical), plus per-block partial
// k-sums for bh=0 written to kpart[64][64] (no atomics, every slot written).
// z==0: q row-major  z==1: k transposed  z==2: v row-major
__global__ __launch_bounds__(256, 4)
void proj_kernel(const float* __restrict__ nodes,
                 const float* __restrict__ Wq, const float* __restrict__ bq,
                 const float* __restrict__ Wk, const float* __restrict__ bk,
                 const float* __restrict__ Wv, const float* __restrict__ bv,
                 float* __restrict__ qf, float* __restrict__ kT,
                 float* __restrict__ vf, float* __restrict__ kpart) {
    const int z = blockIdx.z;
    const float* W; const float* bias; float* out; int mode;
    if (z == 0)      { W = Wq; bias = bq; out = qf; mode = 0; }
    else if (z == 1) { W = Wk; bias = bk; out = kT; mode = 1; }
    else             { W = Wv; bias = bv; out = vf; mode = 0; }

    const int tid = threadIdx.x;
    const int half = blockIdx.x;     // 0..1
    const int r0 = blockIdx.y * 4;   // 4 rows per block

    __shared__ float4 nsh4[4][IN_DIM / 4];   // 4 KB
    {   // stage 4 rows (256 float4), 1 per thread, coalesced
        int rr = tid >> 6, c4 = tid & 63;
        nsh4[rr][c4] = ((const float4*)nodes)[(r0 + rr) * (IN_DIM / 4) + c4];
    }
    __syncthreads();

    const int col = half * 256 + tid;
    float acc[4] = {0.f, 0.f, 0.f, 0.f};
#pragma unroll 4
    for (int kc = 0; kc < IN_DIM / 4; ++kc) {
        float4 n0 = nsh4[0][kc], n1 = nsh4[1][kc], n2 = nsh4[2][kc], n3 = nsh4[3][kc];
        float w0 = W[(kc * 4 + 0) * INNER + col];
        float w1 = W[(kc * 4 + 1) * INNER + col];
        float w2 = W[(kc * 4 + 2) * INNER + col];
        float w3 = W[(kc * 4 + 3) * INNER + col];
        acc[0] += n0.x * w0 + n0.y * w1 + n0.z * w2 + n0.w * w3;
        acc[1] += n1.x * w0 + n1.y * w1 + n1.z * w2 + n1.w * w3;
        acc[2] += n2.x * w0 + n2.y * w1 + n2.z * w2 + n2.w * w3;
        acc[3] += n3.x * w0 + n3.y * w1 + n3.z * w2 + n3.w * w3;
    }
    const float bv2 = bias[col];
    const int h = col >> 6, d = col & 63;
#pragma unroll
    for (int rr = 0; rr < 4; ++rr) {
        int r = r0 + rr;
        int b = r >> 8, n = r & 255;
        float val = acc[rr] + bv2;
        if (mode == 0)
            out[((b * HH + h) * NN + n) * DD + d] = val;
        else
            out[((b * HH + h) * DD + d) * NN + n] = val;
    }
    // partial k-sum for bh=0 (b==0 rows, head 0): 64 y-blocks x 64 d slots
    if (z == 1 && half == 0 && blockIdx.y < 64 && tid < 64) {
        kpart[blockIdx.y * 64 + tid] = acc[0] + acc[1] + acc[2] + acc[3] + 4.f * bv2;
    }
}

// One block per (bh, i-tile of II=8 rows), 256 threads, 512 blocks.
// r6-identical core; means computed in-block from the factorized form:
// means[i] = 0.125*( q0_i·(ksum0/256 + be0) + (esum0_i · t0_i)/256 )
__global__ __launch_bounds__(256, 4)
void attn_kernel(const float* __restrict__ q,
                 const float* __restrict__ kT,
                 const float* __restrict__ v,
                 const float* __restrict__ edges,
                 const float* __restrict__ adj,
                 const float* __restrict__ We,
                 const float* __restrict__ be,
                 const float* __restrict__ kpart,
                 float* __restrict__ out) {
    const int blk = blockIdx.x;           // 512
    const int bh = blk >> 5;
    const int it = blk & 31;
    const int i0 = it * II;
    const int b = bh >> 3, h = bh & 7;
    const int tid = threadIdx.x;          // 0..255
    const int j = tid;
    const int w = tid >> 6;               // wave 0..3

    __shared__ float qsh[II][DD];                 // 2 KB
    __shared__ float q0sh[II][DD];                // 2 KB (bh=0 q rows)
    __shared__ float tsh[II][EDGE_DIM + 1];       // 544 B
    __shared__ float t0sh[II][EDGE_DIM];          // 512 B
    __shared__ float esumsh[II][EDGE_DIM];        // 512 B
    __shared__ float kss[DD];                     // 256 B
    __shared__ float xsh[II][NN];                 // 8 KB (numerators)
    __shared__ float red[4][II][DD];              // 8 KB
    __shared__ float wred2[16][II][EDGE_DIM];     // 8 KB
    __shared__ float wsh[II][EDGE_DIM];
    __shared__ float dred[II][4];
    __shared__ float msh[II];
    __shared__ float dinv[II];
    __shared__ float scoef_sh[II];

    for (int idx = tid; idx < II * DD; idx += 256) {
        int ii = idx >> 6, d = idx & 63;
        qsh[ii][d]  = q[(bh * NN + i0 + ii) * DD + d];
        q0sh[ii][d] = q[(i0 + ii) * DD + d];          // bh = 0
    }
    if (tid < DD) {   // reduce 64 proj partials -> ksum0/256
        float s = 0.f;
#pragma unroll 8
        for (int y = 0; y < 64; ++y) s += kpart[y * 64 + tid];
        kss[tid] = s * (1.f / 256.f);
    }
    __syncthreads();

    if (tid < II * (EDGE_DIM + 1)) {
        int ii = tid / (EDGE_DIM + 1), c = tid % (EDGE_DIM + 1);
        float s = 0.f;
        if (c < EDGE_DIM) {
            for (int d = 0; d < DD; ++d) s += qsh[ii][d] * We[c * INNER + h * DD + d];
        } else {
            for (int d = 0; d < DD; ++d) s += qsh[ii][d] * be[h * DD + d];
        }
        tsh[ii][c] = s;
    }
    if (tid >= 128 && tid < 128 + II * EDGE_DIM) {   // t0 (h=0) in parallel
        int t = tid - 128, ii = t >> 4, c = t & 15;
        float s = 0.f;
        for (int d = 0; d < DD; ++d) s += q0sh[ii][d] * We[c * INNER + d];
        t0sh[ii][c] = s;
    }
    __syncthreads();

    // --- esum0[ii][c] = sum_j edges[0, i0+ii, j, c] (16 partials of 16 j) ---
    {
        const int c = tid & 15, p = tid >> 4;
        float accw[II];
#pragma unroll
        for (int ii = 0; ii < II; ++ii) accw[ii] = 0.f;
        for (int jj = 0; jj < 16; ++jj) {
            int jr = p * 16 + jj;
#pragma unroll
            for (int ii = 0; ii < II; ++ii)
                accw[ii] += edges[((i0 + ii) * NN + jr) * EDGE_DIM + c];   // b = 0
        }
#pragma unroll
        for (int ii = 0; ii < II; ++ii) wred2[p][ii][c] = accw[ii];
    }
    __syncthreads();
    if (tid < II * EDGE_DIM) {
        int ii = tid >> 4, c = tid & 15;
        float t = 0.f;
#pragma unroll
        for (int p = 0; p < 16; ++p) t += wred2[p][ii][c];
        esumsh[ii][c] = t * (1.f / 256.f);
    }
    __syncthreads();
    if (tid < II) {
        float s = 0.f;
        for (int d = 0; d < DD; ++d) s += q0sh[tid][d] * (kss[d] + be[d]);
#pragma unroll
        for (int c = 0; c < EDGE_DIM; ++c) s += esumsh[tid][c] * t0sh[tid][c];
        msh[tid] = s * 0.125f;
    }
    __syncthreads();

    // --- scores: sim[8] accumulated over d (kT read once, reused 8x) ---
    float sim[II];
#pragma unroll
    for (int ii = 0; ii < II; ++ii) sim[ii] = 0.f;
    const float* kbase = &kT[bh * DD * NN];
    for (int d = 0; d < DD; ++d) {
        float kv = kbase[d * NN + j];
#pragma unroll
        for (int ii = 0; ii < II; ++ii) sim[ii] += qsh[ii][d] * kv;
    }

    // --- per row: edge term, exp, mask; numerator -> LDS; denom reduce ---
#pragma unroll
    for (int ii = 0; ii < II; ++ii) {
        const float4* e4 = (const float4*)&edges[((b * NN + i0 + ii) * NN + j) * EDGE_DIM];
        float4 e0 = e4[0], e1 = e4[1], e2 = e4[2], e3 = e4[3];
        float ed = tsh[ii][EDGE_DIM];
        ed += e0.x * tsh[ii][0] + e0.y * tsh[ii][1] + e0.z * tsh[ii][2] + e0.w * tsh[ii][3];
        ed += e1.x * tsh[ii][4] + e1.y * tsh[ii][5] + e1.z * tsh[ii][6] + e1.w * tsh[ii][7];
        ed += e2.x * tsh[ii][8] + e2.y * tsh[ii][9] + e2.z * tsh[ii][10] + e2.w * tsh[ii][11];
        ed += e3.x * tsh[ii][12] + e3.y * tsh[ii][13] + e3.z * tsh[ii][14] + e3.w * tsh[ii][15];
        float s = (sim[ii] + ed) * 0.125f;
        float x = __expf(s - msh[ii]) * adj[(b * NN + i0 + ii) * NN + j];
        xsh[ii][j] = x;
        for (int o = 32; o > 0; o >>= 1) x += __shfl_down(x, o, 64);
        if ((tid & 63) == 0) dred[ii][w] = x;
    }
    __syncthreads();
    if (tid < II) {
        float denom = dred[tid][0] + dred[tid][1] + dred[tid][2] + dred[tid][3];
        scoef_sh[tid] = (denom == 0.f) ? 0.f : 1.f;
        dinv[tid] = (denom == 0.f) ? 1.f : 1.f / denom;
    }
    __syncthreads();

    // --- x @ v (numerators): 4 partials of 64 j, float4 over j ---
    {
        const int d = tid & 63, part = tid >> 6;
        float acc[II];
#pragma unroll
        for (int ii = 0; ii < II; ++ii) acc[ii] = 0.f;
        const float* vb = &v[(bh * NN + part * 64) * DD + d];
        for (int jj4 = 0; jj4 < 16; ++jj4) {
            float av0 = vb[(jj4 * 4 + 0) * DD];
            float av1 = vb[(jj4 * 4 + 1) * DD];
            float av2 = vb[(jj4 * 4 + 2) * DD];
            float av3 = vb[(jj4 * 4 + 3) * DD];
#pragma unroll
            for (int ii = 0; ii < II; ++ii) {
                float4 x4 = *(const float4*)&xsh[ii][part * 64 + jj4 * 4];
                acc[ii] += x4.x * av0 + x4.y * av1 + x4.z * av2 + x4.w * av3;
            }
        }
#pragma unroll
        for (int ii = 0; ii < II; ++ii) red[part][ii][d] = acc[ii];
    }
    // --- w~[ii][c] = sum_j x[ii][j] * edges[b,i0+ii,j,c]: 16 partials of 16 j ---
    {
        const int c = tid & 15, p = tid >> 4;
        float accw[II];
#pragma unroll
        for (int ii = 0; ii < II; ++ii) accw[ii] = 0.f;
        for (int jj = 0; jj < 16; ++jj) {
            int jr = p * 16 + jj;
#pragma unroll
            for (int ii = 0; ii < II; ++ii)
                accw[ii] += xsh[ii][jr] *
                            edges[((b * NN + i0 + ii) * NN + jr) * EDGE_DIM + c];
        }
#pragma unroll
        for (int ii = 0; ii < II; ++ii) wred2[p][ii][c] = accw[ii];
    }
    __syncthreads();
    if (tid < II * EDGE_DIM) {
        int ii = tid >> 4, c = tid & 15;
        float t = 0.f;
#pragma unroll
        for (int p = 0; p < 16; ++p) t += wred2[p][ii][c];
        wsh[ii][c] = t;
    }
    __syncthreads();

    // --- epilogue: normalize once ---
    for (int idx = tid; idx < II * DD; idx += 256) {
        int ii = idx >> 6, d = idx & 63;
        float o = red[0][ii][d] + red[1][ii][d] + red[2][ii][d] + red[3][ii][d];
#pragma unroll
        for (int c = 0; c < EDGE_DIM; ++c)
            o += wsh[ii][c] * We[c * INNER + h * DD + d];
        out[(b * NN + i0 + ii) * INNER + h * DD + d] =
            o * dinv[ii] + scoef_sh[ii] * be[h * DD + d];
    }
}

extern "C" void kernel_launch(void* const* d_in, const int* in_sizes, int n_in,
                              void* d_out, int out_size, void* d_ws, size_t ws_size,
                              hipStream_t stream) {
    const float* nodes = (const float*)d_in[0];
    const float* edges = (const float*)d_in[1];
    const float* adj   = (const float*)d_in[2];
    const float* Wq = (const float*)d_in[3];
    const float* bq = (const float*)d_in[4];
    const float* Wk = (const float*)d_in[5];
    const float* bk = (const float*)d_in[6];
    const float* Wv = (const float*)d_in[7];
    const float* bv = (const float*)d_in[8];
    const float* We = (const float*)d_in[9];
    const float* be = (const float*)d_in[10];
    float* out = (float*)d_out;

    float* qf = (float*)d_ws;            // BH*N*D
    float* kT = qf + BH * NN * DD;       // BH*D*N
    float* vf = kT + BH * NN * DD;       // BH*N*D
    float* kpart = vf + BH * NN * DD;    // 64*64 partial k-sums (bh=0)

    hipLaunchKernelGGL(proj_kernel, dim3(2, 128, 3), dim3(256), 0, stream,
                       nodes, Wq, bq, Wk, bk, Wv, bv, qf, kT, vf, kpart);
    hipLaunchKernelGGL(attn_kernel, dim3(BH * (NN / II)), dim3(256), 0, stream,
                       qf, kT, vf, edges, adj, We, be, kpart, out);
}

// Round 10
// 121.465 us; speedup vs baseline: 2.4987x; 1.0479x over previous
//
#include <hip/hip_runtime.h>
#include <hip/hip_bf16.h>

#define BB 2
#define NN 256
#define IN_DIM 256
#define EDGE_DIM 16
#define HH 8
#define DD 64
#define INNER 512
#define BH (BB*HH)
#define II 8   // i-rows per attn block (r6 proven spill-free shape)

// Fused q/k/v projection, LDS-staged.
// z==0: q row-major  z==1: k transposed  z==2: v row-major
__global__ __launch_bounds__(256, 4)
void proj_kernel(const float* __restrict__ nodes,
                 const float* __restrict__ Wq, const float* __restrict__ bq,
                 const float* __restrict__ Wk, const float* __restrict__ bk,
                 const float* __restrict__ Wv, const float* __restrict__ bv,
                 float* __restrict__ qf, float* __restrict__ kT,
                 float* __restrict__ vf) {
    const int z = blockIdx.z;
    const float* W; const float* bias; float* out; int mode;
    if (z == 0)      { W = Wq; bias = bq; out = qf; mode = 0; }
    else if (z == 1) { W = Wk; bias = bk; out = kT; mode = 1; }
    else             { W = Wv; bias = bv; out = vf; mode = 0; }

    const int tid = threadIdx.x;
    const int half = blockIdx.x;     // 0..1
    const int r0 = blockIdx.y * 4;   // 4 rows per block

    __shared__ float4 nsh4[4][IN_DIM / 4];   // 4 KB
    {   // stage 4 rows (256 float4), 1 per thread, coalesced
        int rr = tid >> 6, c4 = tid & 63;
        nsh4[rr][c4] = ((const float4*)nodes)[(r0 + rr) * (IN_DIM / 4) + c4];
    }
    __syncthreads();

    const int col = half * 256 + tid;
    float acc[4] = {0.f, 0.f, 0.f, 0.f};
#pragma unroll 4
    for (int kc = 0; kc < IN_DIM / 4; ++kc) {
        float4 n0 = nsh4[0][kc], n1 = nsh4[1][kc], n2 = nsh4[2][kc], n3 = nsh4[3][kc];
        float w0 = W[(kc * 4 + 0) * INNER + col];
        float w1 = W[(kc * 4 + 1) * INNER + col];
        float w2 = W[(kc * 4 + 2) * INNER + col];
        float w3 = W[(kc * 4 + 3) * INNER + col];
        acc[0] += n0.x * w0 + n0.y * w1 + n0.z * w2 + n0.w * w3;
        acc[1] += n1.x * w0 + n1.y * w1 + n1.z * w2 + n1.w * w3;
        acc[2] += n2.x * w0 + n2.y * w1 + n2.z * w2 + n2.w * w3;
        acc[3] += n3.x * w0 + n3.y * w1 + n3.z * w2 + n3.w * w3;
    }
    const float bv2 = bias[col];
    const int h = col >> 6, d = col & 63;
#pragma unroll
    for (int rr = 0; rr < 4; ++rr) {
        int r = r0 + rr;
        int b = r >> 8, n = r & 255;
        float val = acc[rr] + bv2;
        if (mode == 0)
            out[((b * HH + h) * NN + n) * DD + d] = val;
        else
            out[((b * HH + h) * DD + d) * NN + n] = val;
    }
}

// One block per (bh, i-tile of II=8 rows), 256 threads, 512 blocks.
// The reference's [0]-sliced mean is a per-row constant inside an
// (adjacency-masked) softmax -> output is exactly invariant to it, including
// the denom==0 path (all-zero adj row => attn row = 0 either way). We use
// m = 0; score magnitudes are small (|s| < ~6) so exp(s) is safe in f32.
__global__ __launch_bounds__(256, 4)
void attn_kernel(const float* __restrict__ q,
                 const float* __restrict__ kT,
                 const float* __restrict__ v,
                 const float* __restrict__ edges,
                 const float* __restrict__ adj,
                 const float* __restrict__ We,
                 const float* __restrict__ be,
                 float* __restrict__ out) {
    const int blk = blockIdx.x;           // 512
    const int bh = blk >> 5;
    const int it = blk & 31;
    const int i0 = it * II;
    const int b = bh >> 3, h = bh & 7;
    const int tid = threadIdx.x;          // 0..255
    const int j = tid;
    const int w = tid >> 6;               // wave 0..3

    __shared__ float qsh[II][DD];                 // 2 KB
    __shared__ float tsh[II][EDGE_DIM + 1];       // 544 B
    __shared__ float xsh[II][NN];                 // 8 KB (numerators)
    __shared__ float red[4][II][DD];              // 8 KB
    __shared__ float wred2[16][II][EDGE_DIM];     // 8 KB
    __shared__ float wsh[II][EDGE_DIM];
    __shared__ float dred[II][4];
    __shared__ float dinv[II];
    __shared__ float scoef_sh[II];

    for (int idx = tid; idx < II * DD; idx += 256) {
        int ii = idx >> 6, d = idx & 63;
        qsh[ii][d] = q[(bh * NN + i0 + ii) * DD + d];
    }
    __syncthreads();

    if (tid < II * (EDGE_DIM + 1)) {
        int ii = tid / (EDGE_DIM + 1), c = tid % (EDGE_DIM + 1);
        float s = 0.f;
        if (c < EDGE_DIM) {
            for (int d = 0; d < DD; ++d) s += qsh[ii][d] * We[c * INNER + h * DD + d];
        } else {
            for (int d = 0; d < DD; ++d) s += qsh[ii][d] * be[h * DD + d];
        }
        tsh[ii][c] = s;
    }
    __syncthreads();

    // --- scores: sim[8] accumulated over d (kT read once, reused 8x) ---
    float sim[II];
#pragma unroll
    for (int ii = 0; ii < II; ++ii) sim[ii] = 0.f;
    const float* kbase = &kT[bh * DD * NN];
    for (int d = 0; d < DD; ++d) {
        float kv = kbase[d * NN + j];
#pragma unroll
        for (int ii = 0; ii < II; ++ii) sim[ii] += qsh[ii][d] * kv;
    }

    // --- per row: edge term, exp, mask; numerator -> LDS; denom reduce ---
#pragma unroll
    for (int ii = 0; ii < II; ++ii) {
        const float4* e4 = (const float4*)&edges[((b * NN + i0 + ii) * NN + j) * EDGE_DIM];
        float4 e0 = e4[0], e1 = e4[1], e2 = e4[2], e3 = e4[3];
        float ed = tsh[ii][EDGE_DIM];
        ed += e0.x * tsh[ii][0] + e0.y * tsh[ii][1] + e0.z * tsh[ii][2] + e0.w * tsh[ii][3];
        ed += e1.x * tsh[ii][4] + e1.y * tsh[ii][5] + e1.z * tsh[ii][6] + e1.w * tsh[ii][7];
        ed += e2.x * tsh[ii][8] + e2.y * tsh[ii][9] + e2.z * tsh[ii][10] + e2.w * tsh[ii][11];
        ed += e3.x * tsh[ii][12] + e3.y * tsh[ii][13] + e3.z * tsh[ii][14] + e3.w * tsh[ii][15];
        float s = (sim[ii] + ed) * 0.125f;
        float x = __expf(s) * adj[(b * NN + i0 + ii) * NN + j];
        xsh[ii][j] = x;
        for (int o = 32; o > 0; o >>= 1) x += __shfl_down(x, o, 64);
        if ((tid & 63) == 0) dred[ii][w] = x;
    }
    __syncthreads();
    if (tid < II) {
        float denom = dred[tid][0] + dred[tid][1] + dred[tid][2] + dred[tid][3];
        scoef_sh[tid] = (denom == 0.f) ? 0.f : 1.f;
        dinv[tid] = (denom == 0.f) ? 1.f : 1.f / denom;
    }
    __syncthreads();

    // --- x @ v (numerators): 4 partials of 64 j, float4 over j ---
    {
        const int d = tid & 63, part = tid >> 6;
        float acc[II];
#pragma unroll
        for (int ii = 0; ii < II; ++ii) acc[ii] = 0.f;
        const float* vb = &v[(bh * NN + part * 64) * DD + d];
        for (int jj4 = 0; jj4 < 16; ++jj4) {
            float av0 = vb[(jj4 * 4 + 0) * DD];
            float av1 = vb[(jj4 * 4 + 1) * DD];
            float av2 = vb[(jj4 * 4 + 2) * DD];
            float av3 = vb[(jj4 * 4 + 3) * DD];
#pragma unroll
            for (int ii = 0; ii < II; ++ii) {
                float4 x4 = *(const float4*)&xsh[ii][part * 64 + jj4 * 4];
                acc[ii] += x4.x * av0 + x4.y * av1 + x4.z * av2 + x4.w * av3;
            }
        }
#pragma unroll
        for (int ii = 0; ii < II; ++ii) red[part][ii][d] = acc[ii];
    }
    // --- w~[ii][c] = sum_j x[ii][j] * edges[b,i0+ii,j,c]: 16 partials of 16 j ---
    {
        const int c = tid & 15, p = tid >> 4;
        float accw[II];
#pragma unroll
        for (int ii = 0; ii < II; ++ii) accw[ii] = 0.f;
        for (int jj = 0; jj < 16; ++jj) {
            int jr = p * 16 + jj;
#pragma unroll
            for (int ii = 0; ii < II; ++ii)
                accw[ii] += xsh[ii][jr] *
                            edges[((b * NN + i0 + ii) * NN + jr) * EDGE_DIM + c];
        }
#pragma unroll
        for (int ii = 0; ii < II; ++ii) wred2[p][ii][c] = accw[ii];
    }
    __syncthreads();
    if (tid < II * EDGE_DIM) {
        int ii = tid >> 4, c = tid & 15;
        float t = 0.f;
#pragma unroll
        for (int p = 0; p < 16; ++p) t += wred2[p][ii][c];
        wsh[ii][c] = t;
    }
    __syncthreads();

    // --- epilogue: normalize once ---
    for (int idx = tid; idx < II * DD; idx += 256) {
        int ii = idx >> 6, d = idx & 63;
        float o = red[0][ii][d] + red[1][ii][d] + red[2][ii][d] + red[3][ii][d];
#pragma unroll
        for (int c = 0; c < EDGE_DIM; ++c)
            o += wsh[ii][c] * We[c * INNER + h * DD + d];
        out[(b * NN + i0 + ii) * INNER + h * DD + d] =
            o * dinv[ii] + scoef_sh[ii] * be[h * DD + d];
    }
}

extern "C" void kernel_launch(void* const* d_in, const int* in_sizes, int n_in,
                              void* d_out, int out_size, void* d_ws, size_t ws_size,
                              hipStream_t stream) {
    const float* nodes = (const float*)d_in[0];
    const float* edges = (const float*)d_in[1];
    const float* adj   = (const float*)d_in[2];
    const float* Wq = (const float*)d_in[3];
    const float* bq = (const float*)d_in[4];
    const float* Wk = (const float*)d_in[5];
    const float* bk = (const float*)d_in[6];
    const float* Wv = (const float*)d_in[7];
    const float* bv = (const float*)d_in[8];
    const float* We = (const float*)d_in[9];
    const float* be = (const float*)d_in[10];
    float* out = (float*)d_out;

    float* qf = (float*)d_ws;            // BH*N*D
    float* kT = qf + BH * NN * DD;       // BH*D*N
    float* vf = kT + BH * NN * DD;       // BH*N*D

    hipLaunchKernelGGL(proj_kernel, dim3(2, 128, 3), dim3(256), 0, stream,
                       nodes, Wq, bq, Wk, bk, Wv, bv, qf, kT, vf);
    hipLaunchKernelGGL(attn_kernel, dim3(BH * (NN / II)), dim3(256), 0, stream,
                       qf, kT, vf, edges, adj, We, be, out);
}